// Round 11
// baseline (723.107 us; speedup 1.0000x reference)
//
#include <hip/hip_runtime.h>
#include <stdint.h>
#include <stddef.h>

#define N_ROWS 262144
#define CCH    256
#define NGRP   4096

typedef short bf16x8 __attribute__((ext_vector_type(8)));
typedef short bf16x4 __attribute__((ext_vector_type(4)));
typedef float f32x4  __attribute__((ext_vector_type(4)));
typedef float f32x16 __attribute__((ext_vector_type(16)));

static __device__ __forceinline__ short f2bf(float f){
  union { float f; unsigned u; } v; v.f = f;
  unsigned u = v.u;
  unsigned r = (u + 0x7FFFu + ((u >> 16) & 1u)) >> 16;   // round-to-nearest-even
  return (short)r;
}

typedef __attribute__((address_space(1))) const unsigned int GU32;
typedef __attribute__((address_space(3))) unsigned int LU32;
static __device__ __forceinline__ void gload_lds16(const void* g, void* l){
  __builtin_amdgcn_global_load_lds((GU32*)g, (LU32*)l, 16, 0, 0);
}

// xb fragment-order layout (shorts):
//   xb[(t*16 + ks)*512 + r*16 + half*8 + j] = x_sorted[p = t*32 + r][k = ks*16 + half*8 + j]
// one MFMA A-frag load (group t, k-step ks) = ONE contiguous 1 KiB chunk.

// ---- cast Wf/Wg to bf16; build Wh transpose (wht[k][j] = Wh[j][k]) ----
__global__ __launch_bounds__(256) void k_castw(
    const float* __restrict__ Wf, const float* __restrict__ Wg,
    const float* __restrict__ Wh,
    short* __restrict__ wfb, short* __restrict__ wgb, float* __restrict__ wht)
{
  int e = blockIdx.x * 256 + threadIdx.x;           // 65536 exact
  wfb[e] = f2bf(Wf[e]);
  wgb[e] = f2bf(Wg[e]);
  int k = e >> 8, j = e & 255;
  wht[e] = Wh[j * 256 + k];
}

// ---- histogram of group ids ----
__global__ __launch_bounds__(256) void k_hist(const int* __restrict__ ix, int* __restrict__ counts){
  int i = blockIdx.x * blockDim.x + threadIdx.x;
  int stride = gridDim.x * blockDim.x;
  for (; i < N_ROWS; i += stride) atomicAdd(&counts[ix[i]], 1);
}

// ---- exclusive prefix sum over 4096 counts -> cursor ----
__global__ __launch_bounds__(1024) void k_scan(const int* __restrict__ counts, int* __restrict__ cursor){
  __shared__ int sums[1024];
  int t = threadIdx.x;
  int base = t * 4;
  int c0 = counts[base], c1 = counts[base+1], c2 = counts[base+2], c3 = counts[base+3];
  sums[t] = c0 + c1 + c2 + c3;
  __syncthreads();
  for (int off = 1; off < 1024; off <<= 1){
    int v = (t >= off) ? sums[t - off] : 0;
    __syncthreads();
    sums[t] += v;
    __syncthreads();
  }
  int prev = (t == 0) ? 0 : sums[t - 1];
  cursor[base]   = prev;
  cursor[base+1] = prev + c0;
  cursor[base+2] = prev + c0 + c1;
  cursor[base+3] = prev + c0 + c1 + c2;
}

// ---- slot assignment only: po[p] = (g, i) ----
__global__ __launch_bounds__(256) void k_slot(
    const int* __restrict__ ix, int* __restrict__ cursor, int2* __restrict__ po)
{
  int i = blockIdx.x * 256 + threadIdx.x;    // 1024 blocks exact
  int g = ix[i];
  int p = atomicAdd(&cursor[g], 1);
  po[p] = make_int2(g, i);
}

// ---- gather + fp32->bf16 cast, writing FRAGMENT-ORDER xb ----
// Block owns 128 contiguous destination slots (64 KiB frag-order region):
// write pieces merge to full lines in L2 (no RMW — r9 fix). unroll 2 ->
// 8 rows / 16 16B-loads in flight per wave.
__global__ __launch_bounds__(256) void k_gather_cast(
    const int2* __restrict__ po, const float* __restrict__ x,
    short* __restrict__ xb)
{
  __shared__ int i_s[128];

  const int tid  = threadIdx.x;
  const int wave = tid >> 6;
  const int lane = tid & 63;
  const int hl   = lane & 31;
  const int sel  = lane >> 5;              // half-wave: 0 -> row A, 1 -> row B

  const int base = blockIdx.x * 128;       // 2048 blocks exact
  if (tid < 128) i_s[tid] = po[base + tid].y;
  __syncthreads();

  const int ks = hl >> 1, half = hl & 1;
  #pragma unroll 2
  for (int pass = wave; pass < 64; pass += 8){
    int slotA = pass * 2 + sel;
    int slotB = (pass + 4) * 2 + sel;
    int srcA = i_s[slotA], dstA = base + slotA;
    int srcB = i_s[slotB], dstB = base + slotB;
    const float* xpA = x + (size_t)srcA * 256 + hl * 8;
    const float* xpB = x + (size_t)srcB * 256 + hl * 8;
    f32x4 a0 = *(const f32x4*)(xpA);
    f32x4 a1 = *(const f32x4*)(xpA + 4);
    f32x4 b0 = *(const f32x4*)(xpB);
    f32x4 b1 = *(const f32x4*)(xpB + 4);
    bf16x8 ba, bb;
    #pragma unroll
    for (int j = 0; j < 4; ++j){
      ba[j] = f2bf(a0[j]); ba[4+j] = f2bf(a1[j]);
      bb[j] = f2bf(b0[j]); bb[4+j] = f2bf(b1[j]);
    }
    int tA = dstA >> 5, rA = dstA & 31;
    int tB = dstB >> 5, rB = dstB & 31;
    *(bf16x8*)(xb + ((size_t)(tA * 16 + ks) * 512 + rA * 16 + half * 8)) = ba;
    *(bf16x8*)(xb + ((size_t)(tB * 16 + ks) * 512 + rB * 16 + half * 8)) = bb;
  }
}

// ---- fused GEMM (fx & gx) + exp + segment reduce, B-stationary persistent ----
// Geometry (verified r5-r10): 32x32x16 MFMA, 4-wave blocks, 32-col slice,
// 32 KiB LDS, grid 2048 = 8 colgroups x 256 rowslots, XCD-swizzled.
// A-loads read fragment-order xb: one contiguous 1 KiB chunk per load.
__global__ __launch_bounds__(256) void k_gemm(
    const short* __restrict__ xb,
    const short* __restrict__ wfb, const short* __restrict__ wgb,
    const float* __restrict__ bfp, const float* __restrict__ bgp,
    const int2* __restrict__ po,
    float* __restrict__ numer, float* __restrict__ denom)
{
  __shared__ short bst[32][512];     // frag f = mat*16 + ks ; 32 KiB

  const int tid  = threadIdx.x;
  const int wave = tid >> 6;
  const int lane = tid & 63;
  const int l31  = lane & 31;
  const int hi   = lane >> 5;

  const int p     = blockIdx.x;          // 2048 blocks
  const int xcd   = p & 7;
  const int ixd   = p >> 3;              // 0..255
  const int cg    = ixd & 7;             // 8 column groups of 32
  const int bslot = xcd * 32 + (ixd >> 3);   // 0..255
  const int j0    = cg * 32;

  // stage B once: 32 frags, 8 per wave
  #pragma unroll
  for (int q = 0; q < 8; ++q){
    int f = wave * 8 + q;
    int mat = f >> 4, ks = f & 15;
    const short* wsrc = mat ? wgb : wfb;
    const short* src = wsrc + (size_t)(j0 + l31) * 256 + ks * 16 + hi * 8;
    gload_lds16(src, &bst[f][0]);
  }
  __syncthreads();   // only barrier in the kernel

  const float bfv = bfp[j0 + l31];
  const float bgv = bgp[j0 + l31];

#define KSTEP(A, KS) do { \
    bf16x8 bF_ = *(const bf16x8*)&bst[(KS)][lane * 8]; \
    accF = __builtin_amdgcn_mfma_f32_32x32x16_bf16((A), bF_, accF, 0, 0, 0); \
    bf16x8 bG_ = *(const bf16x8*)&bst[16 + (KS)][lane * 8]; \
    accG = __builtin_amdgcn_mfma_f32_32x32x16_bf16((A), bG_, accG, 0, 0, 0); \
  } while (0)

  const int aoff = l31 * 16 + hi * 8;    // lane offset within a 1 KiB A-chunk

  #pragma unroll 1
  for (int tile = bslot; tile < N_ROWS / 128; tile += 256){
    const int tgrp = tile * 4 + wave;            // 32-row group id
    const int gidv = po[tgrp * 32 + l31].x;
    const short* xr = xb + (size_t)tgrp * 8192 + aoff;   // 16 KiB per group

    f32x16 accF, accG;
    #pragma unroll
    for (int r = 0; r < 16; ++r){ accF[r] = 0.f; accG[r] = 0.f; }

    // rolling 4-frag groups, name-reused (max 8 live A-frags = 32 regs)
    bf16x8 a0 = *(const bf16x8*)(xr + 0 * 512);
    bf16x8 a1 = *(const bf16x8*)(xr + 1 * 512);
    bf16x8 a2 = *(const bf16x8*)(xr + 2 * 512);
    bf16x8 a3 = *(const bf16x8*)(xr + 3 * 512);
    bf16x8 b0 = *(const bf16x8*)(xr + 4 * 512);
    bf16x8 b1 = *(const bf16x8*)(xr + 5 * 512);
    bf16x8 b2 = *(const bf16x8*)(xr + 6 * 512);
    bf16x8 b3 = *(const bf16x8*)(xr + 7 * 512);
    __builtin_amdgcn_s_setprio(1);
    KSTEP(a0, 0); KSTEP(a1, 1); KSTEP(a2, 2); KSTEP(a3, 3);
    a0 = *(const bf16x8*)(xr + 8 * 512);
    a1 = *(const bf16x8*)(xr + 9 * 512);
    a2 = *(const bf16x8*)(xr + 10 * 512);
    a3 = *(const bf16x8*)(xr + 11 * 512);
    KSTEP(b0, 4); KSTEP(b1, 5); KSTEP(b2, 6); KSTEP(b3, 7);
    b0 = *(const bf16x8*)(xr + 12 * 512);
    b1 = *(const bf16x8*)(xr + 13 * 512);
    b2 = *(const bf16x8*)(xr + 14 * 512);
    b3 = *(const bf16x8*)(xr + 15 * 512);
    KSTEP(a0, 8); KSTEP(a1, 9); KSTEP(a2, 10); KSTEP(a3, 11);
    KSTEP(b0, 12); KSTEP(b1, 13); KSTEP(b2, 14); KSTEP(b3, 15);
    __builtin_amdgcn_s_setprio(0);

    // epilogue: bias + clamp + exp, in-register
    #pragma unroll
    for (int r = 0; r < 16; ++r){
      float g = accG[r] + bgv;
      g = fminf(fmaxf(g, -50.f), 50.f);
      float e = __expf(g);
      accF[r] = (accF[r] + bfv) * e;   // f * e
      accG[r] = e;                     // e
    }

    // segmented reduction over this wave's 32 sorted rows.
    // acc row(r) = (r&3) + 8*(r>>2) + 4*hi ; col = j0 + l31.
    int gprev = __shfl(gidv, (l31 + 31) & 31);
    bool head = (l31 == 0) || (gidv != gprev);
    unsigned long long hb = __ballot(head) & 0xFFFFFFFFull;   // bits 0..31
    if (hb == 1ull){
      // fast path: whole 32-row window is one segment — plain sum
      int g = __shfl(gidv, 0);
      float sF = 0.f, sE = 0.f;
      #pragma unroll
      for (int r = 0; r < 16; ++r){ sF += accF[r]; sE += accG[r]; }
      sF += __shfl_xor(sF, 32);
      sE += __shfl_xor(sE, 32);
      if (hi == 0){
        atomicAdd(&numer[(size_t)g * 256 + j0 + l31], sF);
        atomicAdd(&denom[(size_t)g * 256 + j0 + l31], sE);
      }
    } else {
      int start = 0;
      while (start < 32){
        int g = __shfl(gidv, start);
        unsigned long long rest = hb >> (start + 1);
        int end = rest ? (start + 1 + __builtin_ctzll(rest)) : 32;
        float sF = 0.f, sE = 0.f;
        #pragma unroll
        for (int r = 0; r < 16; ++r){
          int row = (r & 3) + 8 * (r >> 2) + 4 * hi;
          bool in = (row >= start) && (row < end);
          sF += in ? accF[r] : 0.f;
          sE += in ? accG[r] : 0.f;
        }
        sF += __shfl_xor(sF, 32);
        sE += __shfl_xor(sE, 32);
        if (hi == 0){
          atomicAdd(&numer[(size_t)g * 256 + j0 + l31], sF);
          atomicAdd(&denom[(size_t)g * 256 + j0 + l31], sE);
        }
        start = end;
      }
    }
  }
#undef KSTEP
}

// ---- yh[g] = (numer[g]/denom[g]) @ Wh.T + bh ----
__global__ __launch_bounds__(256) void k_yh(
    const float* __restrict__ numer, const float* __restrict__ denom,
    const float* __restrict__ wht, const float* __restrict__ bh,
    float* __restrict__ yh)
{
  __shared__ float ys[8][256];
  int t = threadIdx.x;
  int g0 = blockIdx.x * 8;                 // 512 blocks
  #pragma unroll
  for (int gg = 0; gg < 8; ++gg){
    size_t idx = (size_t)(g0 + gg) * 256 + t;
    float d = denom[idx];
    ys[gg][t] = (d != 0.f) ? (numer[idx] / d) : 0.f;
  }
  __syncthreads();
  float acc[8];
  #pragma unroll
  for (int gg = 0; gg < 8; ++gg) acc[gg] = 0.f;
  for (int k = 0; k < 256; k += 4){
    float w0 = wht[(k+0) * 256 + t];
    float w1 = wht[(k+1) * 256 + t];
    float w2 = wht[(k+2) * 256 + t];
    float w3 = wht[(k+3) * 256 + t];
    #pragma unroll
    for (int gg = 0; gg < 8; ++gg)
      acc[gg] += w0 * ys[gg][k] + w1 * ys[gg][k+1] + w2 * ys[gg][k+2] + w3 * ys[gg][k+3];
  }
  float b = bh[t];
  #pragma unroll
  for (int gg = 0; gg < 8; ++gg) yh[(size_t)(g0 + gg) * 256 + t] = acc[gg] + b;
}

// ---- out[i] = yh[ix[i]] — original row order: SEQUENTIAL 256 MB writes.
// yh (4 MB) is L2/L3-resident so the random reads are cheap (r9 lesson:
// randomness belongs on the read side). ix prefetched one iter ahead. ----
__global__ __launch_bounds__(256) void k_out(const int* __restrict__ ix,
    const float* __restrict__ yh, float* __restrict__ out)
{
  int wave = threadIdx.x >> 6;
  int lane = threadIdx.x & 63;
  int i = blockIdx.x * 4 + wave;
  const int stride = gridDim.x * 4;          // 8192
  int gnext = ix[i];
  for (; i < N_ROWS; i += stride){
    int g = gnext;
    int inext = i + stride;
    if (inext < N_ROWS) gnext = ix[inext];
    f32x4 v = *(const f32x4*)(yh + (size_t)g * 256 + lane * 4);
    *(f32x4*)(out + (size_t)i * 256 + lane * 4) = v;
  }
}

extern "C" void kernel_launch(void* const* d_in, const int* in_sizes, int n_in,
                              void* d_out, int out_size, void* d_ws, size_t ws_size,
                              hipStream_t stream)
{
  const float* x  = (const float*)d_in[0];
  const float* Wf = (const float*)d_in[1];
  const float* bf = (const float*)d_in[2];
  const float* Wg = (const float*)d_in[3];
  const float* bg = (const float*)d_in[4];
  const float* Wh = (const float*)d_in[5];
  const float* bh = (const float*)d_in[6];
  const int*   ix = (const int*)d_in[7];
  float* out = (float*)d_out;

  char* ws = (char*)d_ws;
  float* numer  = (float*)(ws + 0);          // 4 MiB
  float* denom  = (float*)(ws + 4194304);    // 4 MiB
  int*   counts = (int*)  (ws + 8388608);    // 16 KiB
  int*   cursor = (int*)  (ws + 8404992);    // 16 KiB
  float* yh     = (float*)(ws + 8421376);    // 4 MiB
  float* wht    = (float*)(ws + 12615680);   // 256 KiB
  short* wfb    = (short*)(ws + 12877824);   // 128 KiB
  short* wgb    = (short*)(ws + 13008896);   // 128 KiB
  int2*  po     = (int2*) (ws + 13139968);   // 2 MiB

  // fragment-order bf16 x lives in d_out (134 MiB) — dead until k_out runs
  short* xb = (short*)d_out;

  hipMemsetAsync(ws, 0, 8404992, stream);    // numer + denom + counts

  k_castw<<<256, 256, 0, stream>>>(Wf, Wg, Wh, wfb, wgb, wht);
  k_hist<<<512, 256, 0, stream>>>(ix, counts);
  k_scan<<<1, 1024, 0, stream>>>(counts, cursor);
  k_slot<<<1024, 256, 0, stream>>>(ix, cursor, po);
  k_gather_cast<<<2048, 256, 0, stream>>>(po, x, xb);
  k_gemm<<<2048, 256, 0, stream>>>(xb, wfb, wgb, bf, bg, po, numer, denom);
  k_yh<<<512, 256, 0, stream>>>(numer, denom, wht, bh, yh);
  k_out<<<2048, 256, 0, stream>>>(ix, yh, out);
}

// Round 13
// 701.004 us; speedup vs baseline: 1.0315x; 1.0315x over previous
//
#include <hip/hip_runtime.h>
#include <stdint.h>
#include <stddef.h>

#define N_ROWS 262144
#define CCH    256
#define NGRP   4096

typedef short bf16x8 __attribute__((ext_vector_type(8)));
typedef short bf16x4 __attribute__((ext_vector_type(4)));
typedef float f32x4  __attribute__((ext_vector_type(4)));
typedef float f32x16 __attribute__((ext_vector_type(16)));

static __device__ __forceinline__ short f2bf(float f){
  union { float f; unsigned u; } v; v.f = f;
  unsigned u = v.u;
  unsigned r = (u + 0x7FFFu + ((u >> 16) & 1u)) >> 16;   // round-to-nearest-even
  return (short)r;
}

typedef __attribute__((address_space(1))) const unsigned int GU32;
typedef __attribute__((address_space(3))) unsigned int LU32;
static __device__ __forceinline__ void gload_lds16(const void* g, void* l){
  __builtin_amdgcn_global_load_lds((GU32*)g, (LU32*)l, 16, 0, 0);
}

// xb fragment-order layout (shorts):
//   xb[(t*16 + ks)*512 + r*16 + half*8 + j] = x_sorted[p = t*32 + r][k = ks*16 + half*8 + j]
// one MFMA A-frag load (group t, k-step ks) = ONE contiguous 1 KiB chunk.

// ---- cast Wf/Wg to bf16; build Wh transpose (wht[k][j] = Wh[j][k]) ----
__global__ __launch_bounds__(256) void k_castw(
    const float* __restrict__ Wf, const float* __restrict__ Wg,
    const float* __restrict__ Wh,
    short* __restrict__ wfb, short* __restrict__ wgb, float* __restrict__ wht)
{
  int e = blockIdx.x * 256 + threadIdx.x;           // 65536 exact
  wfb[e] = f2bf(Wf[e]);
  wgb[e] = f2bf(Wg[e]);
  int k = e >> 8, j = e & 255;
  wht[e] = Wh[j * 256 + k];
}

// ---- histogram of group ids ----
__global__ __launch_bounds__(256) void k_hist(const int* __restrict__ ix, int* __restrict__ counts){
  int i = blockIdx.x * blockDim.x + threadIdx.x;
  int stride = gridDim.x * blockDim.x;
  for (; i < N_ROWS; i += stride) atomicAdd(&counts[ix[i]], 1);
}

// ---- exclusive prefix sum over 4096 counts -> cursor (+ preserved copy ofs) ----
__global__ __launch_bounds__(1024) void k_scan(const int* __restrict__ counts,
    int* __restrict__ cursor, int* __restrict__ ofs){
  __shared__ int sums[1024];
  int t = threadIdx.x;
  int base = t * 4;
  int c0 = counts[base], c1 = counts[base+1], c2 = counts[base+2], c3 = counts[base+3];
  sums[t] = c0 + c1 + c2 + c3;
  __syncthreads();
  for (int off = 1; off < 1024; off <<= 1){
    int v = (t >= off) ? sums[t - off] : 0;
    __syncthreads();
    sums[t] += v;
    __syncthreads();
  }
  int prev = (t == 0) ? 0 : sums[t - 1];
  int o0 = prev, o1 = prev + c0, o2 = prev + c0 + c1, o3 = prev + c0 + c1 + c2;
  cursor[base] = o0; cursor[base+1] = o1; cursor[base+2] = o2; cursor[base+3] = o3;
  ofs[base]    = o0; ofs[base+1]    = o1; ofs[base+2]    = o2; ofs[base+3]    = o3;
}

// ---- slot assignment only: po[p] = (g, i) ----
__global__ __launch_bounds__(256) void k_slot(
    const int* __restrict__ ix, int* __restrict__ cursor, int2* __restrict__ po)
{
  int i = blockIdx.x * 256 + threadIdx.x;    // 1024 blocks exact
  int g = ix[i];
  int p = atomicAdd(&cursor[g], 1);
  po[p] = make_int2(g, i);
}

// ---- gather + fp32->bf16 cast, writing FRAGMENT-ORDER xb ----
// Block owns 128 contiguous destination slots (64 KiB frag-order region):
// write pieces merge to full lines in L2 (no RMW — r9 fix). Source rows are
// fully-consumed 1 KiB contiguous reads (randomness on the granule-friendly
// read side).
__global__ __launch_bounds__(256) void k_gather_cast(
    const int2* __restrict__ po, const float* __restrict__ x,
    short* __restrict__ xb)
{
  __shared__ int i_s[128];

  const int tid  = threadIdx.x;
  const int wave = tid >> 6;
  const int lane = tid & 63;
  const int hl   = lane & 31;
  const int sel  = lane >> 5;              // half-wave: 0 -> row A, 1 -> row B

  const int base = blockIdx.x * 128;       // 2048 blocks exact
  if (tid < 128) i_s[tid] = po[base + tid].y;
  __syncthreads();

  const int ks = hl >> 1, half = hl & 1;
  // 64 passes of 2 rows; wave handles passes {wave, wave+4, ...}; 2 merged.
  for (int pass = wave; pass < 64; pass += 8){
    int slotA = pass * 2 + sel;
    int slotB = (pass + 4) * 2 + sel;
    int srcA = i_s[slotA], dstA = base + slotA;
    int srcB = i_s[slotB], dstB = base + slotB;
    const float* xpA = x + (size_t)srcA * 256 + hl * 8;
    const float* xpB = x + (size_t)srcB * 256 + hl * 8;
    f32x4 a0 = *(const f32x4*)(xpA);
    f32x4 a1 = *(const f32x4*)(xpA + 4);
    f32x4 b0 = *(const f32x4*)(xpB);
    f32x4 b1 = *(const f32x4*)(xpB + 4);
    bf16x8 ba, bb;
    #pragma unroll
    for (int j = 0; j < 4; ++j){
      ba[j] = f2bf(a0[j]); ba[4+j] = f2bf(a1[j]);
      bb[j] = f2bf(b0[j]); bb[4+j] = f2bf(b1[j]);
    }
    int tA = dstA >> 5, rA = dstA & 31;
    int tB = dstB >> 5, rB = dstB & 31;
    *(bf16x8*)(xb + ((size_t)(tA * 16 + ks) * 512 + rA * 16 + half * 8)) = ba;
    *(bf16x8*)(xb + ((size_t)(tB * 16 + ks) * 512 + rB * 16 + half * 8)) = bb;
  }
}

// ---- fused GEMM (fx & gx) + exp + segment reduce, B-stationary persistent ----
// Geometry (verified r5-r10): 32x32x16 MFMA, 4-wave blocks, 32-col slice,
// 32 KiB LDS, grid 2048 = 8 colgroups x 256 rowslots, XCD-swizzled.
// A-loads read fragment-order xb: one contiguous 1 KiB chunk per load.
__global__ __launch_bounds__(256) void k_gemm(
    const short* __restrict__ xb,
    const short* __restrict__ wfb, const short* __restrict__ wgb,
    const float* __restrict__ bfp, const float* __restrict__ bgp,
    const int2* __restrict__ po,
    float* __restrict__ numer, float* __restrict__ denom)
{
  __shared__ short bst[32][512];     // frag f = mat*16 + ks ; 32 KiB

  const int tid  = threadIdx.x;
  const int wave = tid >> 6;
  const int lane = tid & 63;
  const int l31  = lane & 31;
  const int hi   = lane >> 5;

  const int p     = blockIdx.x;          // 2048 blocks
  const int xcd   = p & 7;
  const int ixd   = p >> 3;              // 0..255
  const int cg    = ixd & 7;             // 8 column groups of 32
  const int bslot = xcd * 32 + (ixd >> 3);   // 0..255
  const int j0    = cg * 32;

  // stage B once: 32 frags, 8 per wave
  #pragma unroll
  for (int q = 0; q < 8; ++q){
    int f = wave * 8 + q;
    int mat = f >> 4, ks = f & 15;
    const short* wsrc = mat ? wgb : wfb;
    const short* src = wsrc + (size_t)(j0 + l31) * 256 + ks * 16 + hi * 8;
    gload_lds16(src, &bst[f][0]);
  }
  __syncthreads();   // only barrier in the kernel

  const float bfv = bfp[j0 + l31];
  const float bgv = bgp[j0 + l31];

#define KSTEP(A, KS) do { \
    bf16x8 bF_ = *(const bf16x8*)&bst[(KS)][lane * 8]; \
    accF = __builtin_amdgcn_mfma_f32_32x32x16_bf16((A), bF_, accF, 0, 0, 0); \
    bf16x8 bG_ = *(const bf16x8*)&bst[16 + (KS)][lane * 8]; \
    accG = __builtin_amdgcn_mfma_f32_32x32x16_bf16((A), bG_, accG, 0, 0, 0); \
  } while (0)

  const int aoff = l31 * 16 + hi * 8;    // lane offset within a 1 KiB A-chunk

  #pragma unroll 1
  for (int tile = bslot; tile < N_ROWS / 128; tile += 256){
    const int tgrp = tile * 4 + wave;            // 32-row group id
    const int gidv = po[tgrp * 32 + l31].x;
    const short* xr = xb + (size_t)tgrp * 8192 + aoff;   // 16 KiB per group

    f32x16 accF, accG;
    #pragma unroll
    for (int r = 0; r < 16; ++r){ accF[r] = 0.f; accG[r] = 0.f; }

    // rolling 4-frag groups, name-reused (max 8 live A-frags = 32 regs)
    bf16x8 a0 = *(const bf16x8*)(xr + 0 * 512);
    bf16x8 a1 = *(const bf16x8*)(xr + 1 * 512);
    bf16x8 a2 = *(const bf16x8*)(xr + 2 * 512);
    bf16x8 a3 = *(const bf16x8*)(xr + 3 * 512);
    bf16x8 b0 = *(const bf16x8*)(xr + 4 * 512);
    bf16x8 b1 = *(const bf16x8*)(xr + 5 * 512);
    bf16x8 b2 = *(const bf16x8*)(xr + 6 * 512);
    bf16x8 b3 = *(const bf16x8*)(xr + 7 * 512);
    __builtin_amdgcn_s_setprio(1);
    KSTEP(a0, 0); KSTEP(a1, 1); KSTEP(a2, 2); KSTEP(a3, 3);
    a0 = *(const bf16x8*)(xr + 8 * 512);
    a1 = *(const bf16x8*)(xr + 9 * 512);
    a2 = *(const bf16x8*)(xr + 10 * 512);
    a3 = *(const bf16x8*)(xr + 11 * 512);
    KSTEP(b0, 4); KSTEP(b1, 5); KSTEP(b2, 6); KSTEP(b3, 7);
    b0 = *(const bf16x8*)(xr + 12 * 512);
    b1 = *(const bf16x8*)(xr + 13 * 512);
    b2 = *(const bf16x8*)(xr + 14 * 512);
    b3 = *(const bf16x8*)(xr + 15 * 512);
    KSTEP(a0, 8); KSTEP(a1, 9); KSTEP(a2, 10); KSTEP(a3, 11);
    KSTEP(b0, 12); KSTEP(b1, 13); KSTEP(b2, 14); KSTEP(b3, 15);
    __builtin_amdgcn_s_setprio(0);

    // epilogue: bias + clamp + exp, in-register
    #pragma unroll
    for (int r = 0; r < 16; ++r){
      float g = accG[r] + bgv;
      g = fminf(fmaxf(g, -50.f), 50.f);
      float e = __expf(g);
      accF[r] = (accF[r] + bfv) * e;   // f * e
      accG[r] = e;                     // e
    }

    // segmented reduction over this wave's 32 sorted rows.
    // acc row(r) = (r&3) + 8*(r>>2) + 4*hi ; col = j0 + l31.
    int gprev = __shfl(gidv, (l31 + 31) & 31);
    bool head = (l31 == 0) || (gidv != gprev);
    unsigned long long hb = __ballot(head) & 0xFFFFFFFFull;   // bits 0..31
    if (hb == 1ull){
      // fast path: whole 32-row window is one segment — plain sum
      int g = __shfl(gidv, 0);
      float sF = 0.f, sE = 0.f;
      #pragma unroll
      for (int r = 0; r < 16; ++r){ sF += accF[r]; sE += accG[r]; }
      sF += __shfl_xor(sF, 32);
      sE += __shfl_xor(sE, 32);
      if (hi == 0){
        atomicAdd(&numer[(size_t)g * 256 + j0 + l31], sF);
        atomicAdd(&denom[(size_t)g * 256 + j0 + l31], sE);
      }
    } else {
      int start = 0;
      while (start < 32){
        int g = __shfl(gidv, start);
        unsigned long long rest = hb >> (start + 1);
        int end = rest ? (start + 1 + __builtin_ctzll(rest)) : 32;
        float sF = 0.f, sE = 0.f;
        #pragma unroll
        for (int r = 0; r < 16; ++r){
          int row = (r & 3) + 8 * (r >> 2) + 4 * hi;
          bool in = (row >= start) && (row < end);
          sF += in ? accF[r] : 0.f;
          sE += in ? accG[r] : 0.f;
        }
        sF += __shfl_xor(sF, 32);
        sE += __shfl_xor(sE, 32);
        if (hi == 0){
          atomicAdd(&numer[(size_t)g * 256 + j0 + l31], sF);
          atomicAdd(&denom[(size_t)g * 256 + j0 + l31], sE);
        }
        start = end;
      }
    }
  }
#undef KSTEP
}

// ---- yh + broadcast fused: compute yh[g] = (numer/denom)@Wh.T + bh in LDS,
// then write it directly to every output row of group g (rows are the
// contiguous po-range [ofs[g], ofs[g]+counts[g]) — counting-sort property).
// Kills the 4 MB yh round-trip AND the whole k_out kernel; writes are the
// same full-line 1 KiB row bursts k_out did (no RMW), reads now LDS-local.
__global__ __launch_bounds__(256) void k_yh_out(
    const float* __restrict__ numer, const float* __restrict__ denom,
    const float* __restrict__ wht, const float* __restrict__ bh,
    const int* __restrict__ ofs, const int* __restrict__ counts,
    const int2* __restrict__ po, float* __restrict__ out)
{
  __shared__ float ys[8][256];
  int t = threadIdx.x;
  int g0 = blockIdx.x * 8;                 // 512 blocks
  #pragma unroll
  for (int gg = 0; gg < 8; ++gg){
    size_t idx = (size_t)(g0 + gg) * 256 + t;
    float d = denom[idx];
    ys[gg][t] = (d != 0.f) ? (numer[idx] / d) : 0.f;
  }
  __syncthreads();
  float acc[8];
  #pragma unroll
  for (int gg = 0; gg < 8; ++gg) acc[gg] = 0.f;
  for (int k = 0; k < 256; k += 4){
    float w0 = wht[(k+0) * 256 + t];
    float w1 = wht[(k+1) * 256 + t];
    float w2 = wht[(k+2) * 256 + t];
    float w3 = wht[(k+3) * 256 + t];
    #pragma unroll
    for (int gg = 0; gg < 8; ++gg)
      acc[gg] += w0 * ys[gg][k] + w1 * ys[gg][k+1] + w2 * ys[gg][k+2] + w3 * ys[gg][k+3];
  }
  float b = bh[t];
  __syncthreads();
  #pragma unroll
  for (int gg = 0; gg < 8; ++gg) ys[gg][t] = acc[gg] + b;   // final rows -> LDS
  __syncthreads();

  // broadcast: each wave streams 1 KiB rows for its share of each group
  const int wave = t >> 6;
  const int lane = t & 63;
  for (int gg = 0; gg < 8; ++gg){
    int g = g0 + gg;
    int o = ofs[g], cnt = counts[g];
    f32x4 v = *(const f32x4*)&ys[gg][lane * 4];
    for (int idx = wave; idx < cnt; idx += 4){
      int dst = po[o + idx].y;
      *(f32x4*)(out + (size_t)dst * 256 + lane * 4) = v;
    }
  }
}

extern "C" void kernel_launch(void* const* d_in, const int* in_sizes, int n_in,
                              void* d_out, int out_size, void* d_ws, size_t ws_size,
                              hipStream_t stream)
{
  const float* x  = (const float*)d_in[0];
  const float* Wf = (const float*)d_in[1];
  const float* bf = (const float*)d_in[2];
  const float* Wg = (const float*)d_in[3];
  const float* bg = (const float*)d_in[4];
  const float* Wh = (const float*)d_in[5];
  const float* bh = (const float*)d_in[6];
  const int*   ix = (const int*)d_in[7];
  float* out = (float*)d_out;

  char* ws = (char*)d_ws;
  float* numer  = (float*)(ws + 0);          // 4 MiB
  float* denom  = (float*)(ws + 4194304);    // 4 MiB
  int*   counts = (int*)  (ws + 8388608);    // 16 KiB
  int*   cursor = (int*)  (ws + 8404992);    // 16 KiB
  int*   ofs    = (int*)  (ws + 8421376);    // 16 KiB (preserved scan result)
  float* wht    = (float*)(ws + 12615680);   // 256 KiB
  short* wfb    = (short*)(ws + 12877824);   // 128 KiB
  short* wgb    = (short*)(ws + 13008896);   // 128 KiB
  int2*  po     = (int2*) (ws + 13139968);   // 2 MiB

  // fragment-order bf16 x lives in d_out (134 MiB) — dead until k_yh_out runs
  short* xb = (short*)d_out;

  hipMemsetAsync(ws, 0, 8404992, stream);    // numer + denom + counts

  k_castw<<<256, 256, 0, stream>>>(Wf, Wg, Wh, wfb, wgb, wht);
  k_hist<<<512, 256, 0, stream>>>(ix, counts);
  k_scan<<<1, 1024, 0, stream>>>(counts, cursor, ofs);
  k_slot<<<1024, 256, 0, stream>>>(ix, cursor, po);
  k_gather_cast<<<2048, 256, 0, stream>>>(po, x, xb);
  k_gemm<<<2048, 256, 0, stream>>>(xb, wfb, wgb, bf, bg, po, numer, denom);
  k_yh_out<<<512, 256, 0, stream>>>(numer, denom, wht, bh, ofs, counts, po, out);
}